// Round 20
// baseline (272.678 us; speedup 1.0000x reference)
//
#include <hip/hip_runtime.h>
#include <math.h>

#define LEN_IN_C 20197
#define BATCH_C 2
#define BL_C (BATCH_C * LEN_IN_C)   // 40394

typedef short  bf16x8 __attribute__((ext_vector_type(8)));
typedef float  f32x4  __attribute__((ext_vector_type(4)));

__device__ __forceinline__ ushort f2bf(float f) {
    unsigned u = __float_as_uint(f);
    return (ushort)((u + 0x7fffu + ((u >> 16) & 1u)) >> 16);
}
__device__ __forceinline__ float bf2f(ushort u) {
    return __uint_as_float((uint)u << 16);
}
__device__ __forceinline__ uint pkbf(float a, float b) {
    uint r;
    asm("v_cvt_pk_bf16_f32 %0, %1, %2" : "=v"(r) : "v"(a), "v"(b));
    return r;
}
// acc += v.lo*w.lo + v.hi*w.hi  (bf16 pairs, f32 accumulate)
__device__ __forceinline__ void dot2bf(float& a, uint v, uint w) {
    asm("v_dot2_f32_bf16 %0, %1, %2, %0" : "+v"(a) : "v"(v), "v"(w));
}
__device__ __forceinline__ void gload16(const void* g, void* l) {
    __builtin_amdgcn_global_load_lds(
        (const __attribute__((address_space(1))) unsigned char*)g,
        (__attribute__((address_space(3))) unsigned char*)l, 16, 0, 0);
}
__device__ __forceinline__ int xcd_swz(int lid, int nwg) {
    const int q = nwg >> 3, r = nwg & 7;
    const int xcd = lid & 7, p = lid >> 3;
    return (xcd < r ? xcd * (q + 1) : r * (q + 1) + (xcd - r) * q) + p;
}

// ================= combined prep kernel (weights + q + src_bf) =================
__device__ __forceinline__ void tcast32(
    const float* W, ushort* WT, int K, int N, int n0, int k0, float* tile /*32*33*/)
{
    const int ty = threadIdx.x >> 3, tx = threadIdx.x & 7;
    float4 v = *(const float4*)(W + (size_t)(k0 + ty) * N + n0 + tx * 4);
    tile[ty * 33 + tx * 4 + 0] = v.x; tile[ty * 33 + tx * 4 + 1] = v.y;
    tile[ty * 33 + tx * 4 + 2] = v.z; tile[ty * 33 + tx * 4 + 3] = v.w;
    __syncthreads();
    ushort4 o;
    o.x = f2bf(tile[(tx * 4 + 0) * 33 + ty]);
    o.y = f2bf(tile[(tx * 4 + 1) * 33 + ty]);
    o.z = f2bf(tile[(tx * 4 + 2) * 33 + ty]);
    o.w = f2bf(tile[(tx * 4 + 3) * 33 + ty]);
    *(ushort4*)(WT + (size_t)(n0 + ty) * K + k0 + tx * 4) = o;
}

__global__ __launch_bounds__(256) void prep_all(
    const float* __restrict__ src, const float* __restrict__ pos,
    const float* __restrict__ Wv, const float* __restrict__ Wo,
    const float* __restrict__ Wa, const float* __restrict__ Wout,
    const float* __restrict__ W1, const float* __restrict__ W2,
    const float* __restrict__ bo, const float* __restrict__ ba,
    ushort* __restrict__ Tval, ushort* __restrict__ Toa,
    ushort* __restrict__ Tout, ushort* __restrict__ TW1,
    ushort* __restrict__ TW2, float* __restrict__ boa,
    ushort* __restrict__ qout, ushort* __restrict__ srcb)
{
    __shared__ float tile[32 * 33];
    const int bx = blockIdx.x;
    const int tid = threadIdx.x;
    if (bx < 64) {
        tcast32(Wv, Tval, 256, 256, (bx & 7) * 32, (bx >> 3) * 32, tile);
    } else if (bx < 128) {
        const int s = bx - 64;
        tcast32(Wout, Tout, 256, 256, (s & 7) * 32, (s >> 3) * 32, tile);
    } else if (bx < 384) {
        const int s = bx - 128;
        tcast32(W1, TW1, 256, 1024, (s & 31) * 32, (s >> 5) * 32, tile);
    } else if (bx < 640) {
        const int s = bx - 384;
        tcast32(W2, TW2, 1024, 256, (s & 7) * 32, (s >> 3) * 32, tile);
    } else if (bx < 736) {
        const int idx = (bx - 640) * 256 + tid;
        const int n = idx >> 6, k4 = (idx & 63) * 4;
        ushort4 o; ushort* po = (ushort*)&o;
        #pragma unroll
        for (int j = 0; j < 4; ++j) {
            const int k = k4 + j;
            const float v = (n < 256) ? Wo[(size_t)k * 256 + n]
                                      : Wa[(size_t)k * 128 + (n - 256)];
            po[j] = f2bf(v);
        }
        *(ushort4*)(Toa + (size_t)n * 256 + k4) = o;
    } else if (bx < 738) {
        const int n = (bx - 736) * 256 + tid;
        if (n < 384) boa[n] = (n < 256) ? bo[n] : ba[n - 256];
    } else {
        const int n8 = BL_C * 32;
        for (int i = (bx - 738) * 256 + tid; i < n8; i += 1024 * 256) {
            const size_t base = (size_t)i * 8;
            float4 a0 = *(const float4*)(src + base);
            float4 a1 = *(const float4*)(src + base + 4);
            float4 b0 = *(const float4*)(pos + base);
            float4 b1 = *(const float4*)(pos + base + 4);
            uint4 o;
            o.x = pkbf(a0.x + b0.x, a0.y + b0.y);
            o.y = pkbf(a0.z + b0.z, a0.w + b0.w);
            o.z = pkbf(a1.x + b1.x, a1.y + b1.y);
            o.w = pkbf(a1.z + b1.z, a1.w + b1.w);
            *(uint4*)(qout + base) = o;
            uint4 s4;
            s4.x = pkbf(a0.x, a0.y); s4.y = pkbf(a0.z, a0.w);
            s4.z = pkbf(a1.x, a1.y); s4.w = pkbf(a1.z, a1.w);
            *(uint4*)(srcb + base) = s4;
        }
    }
}

// ====== B-PERSISTENT MFMA GEMM (K=256, small L only): whole-K B in 64KB LDS ======
// Block stages its 128-col x 256-K B-tile ONCE (16 gload16 + 1 barrier), then a
// barrier-free M-loop over L row-tiles of 128. GOOD for L<=2 (r19: dual/G3
// improved ~25-30us); BAD for L=4 (G4 86us: 248 VGPR + 64KB -> no TLP).
template <int L, bool RELU>
__device__ __forceinline__ void gemm_pers_core(
    ushort* lsB,  // 128 x 256 bf16 = 64KB
    const int lid,
    const ushort* __restrict__ A, const ushort* __restrict__ BT,
    const float* __restrict__ bias, ushort* __restrict__ C,
    const int M, const int N, const int NT, const int P, const int nwg)
{
    const int nid = xcd_swz(lid, nwg);
    const int nt = nid % NT, p0 = nid / NT;
    const int col0 = nt * 128;

    const int tid = threadIdx.x;
    const int ln = tid & 63, wv = tid >> 6;
    const int l16 = ln & 15, lk = ln >> 4;

    // ---- stage whole B-tile (128 rows x 256 K = 4096 chunks, 32/row) ----
    #pragma unroll
    for (int j = 0; j < 16; ++j) {
        const int d = j * 256 + tid;
        const int brow = d >> 5;
        const int c = (d & 31) ^ (brow & 7);
        gload16(BT + (size_t)(col0 + brow) * 256 + c * 8,
                (char*)lsB + j * 4096 + wv * 1024);
    }

    uint bbase[8], bxor[8];
    #pragma unroll
    for (int n = 0; n < 8; ++n) {
        const int brow = n * 16 + l16;
        bbase[n] = (uint)(brow * 512 + lk * 16);
        bxor[n]  = (uint)((brow & 7) << 4);
    }

    // ---- prologue: A for first tile (overlaps stage; no LDS dependence) ----
    bf16x8 ar[8][2];
    {
        const int row0 = p0 * 128;
        #pragma unroll
        for (int s = 0; s < 8; ++s)
            #pragma unroll
            for (int m = 0; m < 2; ++m) {
                int rr = row0 + wv * 32 + m * 16 + l16;
                if (rr > M - 1) rr = M - 1;
                ar[s][m] = *(const bf16x8*)(A + (uint)rr * 256 + lk * 8 + s * 32);
            }
    }
    __syncthreads();   // drains vmcnt(0): B in LDS AND A in regs

    float4 bias4[8];
    #pragma unroll
    for (int n = 0; n < 8; ++n)
        bias4[n] = *(const float4*)(bias + col0 + n * 16 + lk * 4);

    #pragma unroll
    for (int i = 0; i < L; ++i) {
        const int mt = p0 + i * P;
        const int row0 = mt * 128;

        f32x4 acc[2][8] = {};
        #pragma unroll
        for (int gs = 0; gs < 8; ++gs) {
            bf16x8 bv[8];
            #pragma unroll
            for (int n = 0; n < 8; ++n)
                bv[n] = *(const bf16x8*)((const char*)lsB +
                        ((bbase[n] + gs * 64) ^ bxor[n]));
            #pragma unroll
            for (int m = 0; m < 2; ++m)
                #pragma unroll
                for (int n = 0; n < 8; ++n)
                    acc[m][n] = __builtin_amdgcn_mfma_f32_16x16x32_bf16(
                        bv[n], ar[gs][m], acc[m][n], 0, 0, 0);
        }

        // prefetch next tile's A into the (now-consumed) ring
        if (i + 1 < L) {
            const int nrow0 = (mt + P) * 128;
            #pragma unroll
            for (int s = 0; s < 8; ++s)
                #pragma unroll
                for (int m = 0; m < 2; ++m) {
                    int rr = nrow0 + wv * 32 + m * 16 + l16;
                    if (rr > M - 1) rr = M - 1;
                    ar[s][m] = *(const bf16x8*)(A + (uint)rr * 256 + lk * 8 + s * 32);
                }
        }

        // epilogue for this tile (covers next-A latency)
        #pragma unroll
        for (int m = 0; m < 2; ++m) {
            const int grow = row0 + wv * 32 + m * 16 + l16;
            if (grow >= M) continue;
            ushort* crow = C + (size_t)grow * N;
            #pragma unroll
            for (int n = 0; n < 8; ++n) {
                const int col4 = col0 + n * 16 + lk * 4;
                f32x4 v = acc[m][n];
                float o0 = v[0] + bias4[n].x, o1 = v[1] + bias4[n].y;
                float o2 = v[2] + bias4[n].z, o3 = v[3] + bias4[n].w;
                if (RELU) {
                    o0 = fmaxf(o0, 0.f); o1 = fmaxf(o1, 0.f);
                    o2 = fmaxf(o2, 0.f); o3 = fmaxf(o3, 0.f);
                }
                *(uint2*)(crow + col4) = make_uint2(pkbf(o0, o1), pkbf(o2, o3));
            }
        }
    }
}

template <int L, bool RELU>
__global__ __launch_bounds__(256) void gemm_pers(
    const ushort* __restrict__ A, const ushort* __restrict__ BT,
    const float* __restrict__ bias, ushort* __restrict__ C,
    const int M, const int N, const int NT, const int P, const int nwg)
{
    __shared__ ushort lsB[128 * 256];   // 64KB
    gemm_pers_core<L, RELU>(lsB, blockIdx.x, A, BT, bias, C, M, N, NT, P, nwg);
}

// Dual-task persistent GEMM (both K=256, L=2).
__global__ __launch_bounds__(256) void gemm_dual(
    const ushort* __restrict__ A1, const ushort* __restrict__ BT1,
    const float* __restrict__ b1, ushort* __restrict__ C1,
    const int N1, const int NT1, const int P1, const int nwg1,
    const ushort* __restrict__ A2, const ushort* __restrict__ BT2,
    const float* __restrict__ b2, ushort* __restrict__ C2,
    const int N2, const int NT2, const int P2, const int nwg2)
{
    __shared__ ushort lsB[128 * 256];   // 64KB
    if ((int)blockIdx.x < nwg1)
        gemm_pers_core<2, false>(lsB, blockIdx.x, A1, BT1, b1, C1, BL_C, N1, NT1, P1, nwg1);
    else
        gemm_pers_core<2, false>(lsB, blockIdx.x - nwg1, A2, BT2, b2, C2, BL_C, N2, NT2, P2, nwg2);
}

// ====== chunked GEMM (round-18 proven): m=2, n=8, KC=128, 32KB LDS ======
template <bool RELU>
__global__ __launch_bounds__(256) void gemm_bs(
    const ushort* __restrict__ A, const ushort* __restrict__ BT,
    const float* __restrict__ bias, ushort* __restrict__ C,
    const int M, const int N, const int K, const int NT, const int nwg)
{
    __shared__ ushort lsB[128 * 128];   // 32KB

    const int nid = xcd_swz(blockIdx.x, nwg);
    const int nt = nid % NT, mt = nid / NT;
    const int row0 = mt * 128, col0 = nt * 128;

    const int tid = threadIdx.x;
    const int ln = tid & 63, wv = tid >> 6;
    const int l16 = ln & 15, lk = ln >> 4;

    uint abase[2];
    #pragma unroll
    for (int m = 0; m < 2; ++m) {
        int rr = row0 + wv * 32 + m * 16 + l16;
        if (rr > M - 1) rr = M - 1;
        abase[m] = (uint)rr * K + lk * 8;
    }
    uint bbase[8], bxor[8];
    #pragma unroll
    for (int n = 0; n < 8; ++n) {
        const int brow = n * 16 + l16;
        bbase[n] = (uint)(brow * 256 + lk * 16);
        bxor[n]  = (uint)((brow & 7) << 4);
    }

    f32x4 acc[2][8] = {};
    const int nch = K >> 7;

    for (int ch = 0; ch < nch; ++ch) {
        const int kc0 = ch << 7;

        bf16x8 ar[4][2];
        #pragma unroll
        for (int s = 0; s < 4; ++s)
            #pragma unroll
            for (int m = 0; m < 2; ++m)
                ar[s][m] = *(const bf16x8*)(A + abase[m] + kc0 + s * 32);

        if (ch) __syncthreads();
        #pragma unroll
        for (int j = 0; j < 8; ++j) {
            const int d = j * 256 + tid;
            const int brow = d >> 4;
            const int c = (d & 15) ^ (brow & 7);
            gload16(BT + (size_t)(col0 + brow) * K + kc0 + c * 8,
                    (char*)lsB + j * 4096 + wv * 1024);
        }
        __syncthreads();   // drains vmcnt(0): B in LDS AND A in regs

        #pragma unroll
        for (int gs = 0; gs < 4; ++gs) {
            bf16x8 bv[8];
            #pragma unroll
            for (int n = 0; n < 8; ++n)
                bv[n] = *(const bf16x8*)((const char*)lsB +
                        ((bbase[n] + gs * 64) ^ bxor[n]));
            #pragma unroll
            for (int m = 0; m < 2; ++m)
                #pragma unroll
                for (int n = 0; n < 8; ++n)
                    acc[m][n] = __builtin_amdgcn_mfma_f32_16x16x32_bf16(
                        bv[n], ar[gs][m], acc[m][n], 0, 0, 0);
        }
    }

    #pragma unroll
    for (int m = 0; m < 2; ++m) {
        const int grow = row0 + wv * 32 + m * 16 + l16;
        if (grow >= M) continue;
        ushort* crow = C + (size_t)grow * N;
        #pragma unroll
        for (int n = 0; n < 8; ++n) {
            const int col4 = col0 + n * 16 + lk * 4;
            float4 bs = *(const float4*)(bias + col4);
            f32x4 v = acc[m][n];
            float o0 = v[0] + bs.x, o1 = v[1] + bs.y, o2 = v[2] + bs.z, o3 = v[3] + bs.w;
            if (RELU) {
                o0 = fmaxf(o0, 0.f); o1 = fmaxf(o1, 0.f);
                o2 = fmaxf(o2, 0.f); o3 = fmaxf(o3, 0.f);
            }
            *(uint2*)(crow + col4) = make_uint2(pkbf(o0, o1), pkbf(o2, o3));
        }
    }
}

// ================= MS-deformable sampling: 1 block = 8 queries =================
__global__ __launch_bounds__(256) void sample_kernel(
    const ushort* __restrict__ value,    // (B, L, 256) bf16
    const ushort* __restrict__ oa,       // (BL, 384) bf16: [off 256 | attn 128]
    const float* __restrict__ ref,       // (BL, 8)
    ushort* __restrict__ outbf)          // (BL, 256) bf16
{
    constexpr int Hs[4] = {100, 50, 25, 13};
    constexpr int Ws[4] = {152, 76, 38, 19};
    constexpr int St[4] = {0, 15200, 19000, 19950};
    constexpr int NWG = (BL_C + 7) / 8;    // 5050

    const int bq0 = xcd_swz(blockIdx.x, NWG) * 8;
    const int t = threadIdx.x;

    __shared__ uint2 s_pw[8][8][33];   // [q][h][pair j=i*2+dy], 16.9 KB

    // ---- phase 1: 4 rounds x 2 queries; each lane owns one (h, l, p) ----
    #pragma unroll
    for (int rnd = 0; rnd < 4; ++rnd) {
        const int qi2 = t >> 7, r2 = t & 127;
        const int qloc = rnd * 2 + qi2;
        int bq = bq0 + qloc; if (bq > BL_C - 1) bq = BL_C - 1;
        const int b = (bq >= LEN_IN_C) ? 1 : 0;
        const int h = r2 >> 4, i = r2 & 15, l = i >> 2, p = i & 3;
        const ushort* crow = oa + (size_t)bq * 384;

        float lg = bf2f(crow[256 + h * 16 + i]);
        float mx = lg;
        #pragma unroll
        for (int o = 1; o < 16; o <<= 1) mx = fmaxf(mx, __shfl_xor(mx, o, 16));
        float e = __expf(lg - mx), sm = e;
        #pragma unroll
        for (int o = 1; o < 16; o <<= 1) sm += __shfl_xor(sm, o, 16);
        const float aw = e / sm;

        const uint ov = *(const uint*)(crow + h * 32 + l * 8 + p * 2);
        const float ox = __uint_as_float(ov << 16);
        const float oy = __uint_as_float(ov & 0xffff0000u);
        const float2 rxy = *(const float2*)(ref + (size_t)bq * 8 + l * 2);
        const int H = Hs[l], W = Ws[l];
        const float x = rxy.x * (float)W + ox - 0.5f;
        const float y = rxy.y * (float)H + oy - 0.5f;
        const float x0f = floorf(x), y0f = floorf(y);
        const float fx = x - x0f, fy = y - y0f;
        const int x0 = (int)x0f, y0 = (int)y0f;

        const float wx0 = (x0 >= 0 && x0 < W) ? (1.f - fx) : 0.f;
        const float wx1 = (x0 + 1 >= 0 && x0 + 1 < W) ? fx : 0.f;
        int xb = x0 < 0 ? 0 : (x0 > W - 2 ? W - 2 : x0);
        float wLx = (xb == x0) ? wx0 : ((xb == x0 + 1) ? wx1 : 0.f);
        float wRx = (xb + 1 == x0 + 1) ? wx1 : ((xb + 1 == x0) ? wx0 : 0.f);
        wLx *= aw; wRx *= aw;

        const uint rowb = (uint)(b * LEN_IN_C + St[l] + xb);
        #pragma unroll
        for (int dy = 0; dy < 2; ++dy) {
            const int yy = y0 + dy;
            const bool vy = (yy >= 0) & (yy < H);
            const float wy = vy ? (dy ? fy : 1.f - fy) : 0.f;
            const int yc = yy < 0 ? 0 : (yy > H - 1 ? H - 1 : yy);
            const uint off = (rowb + (uint)(yc * W)) * 512u;
            // bf16 pair, order (lo=wR, hi=wL) to match perm output {lo:vR, hi:vL}
            s_pw[qloc][h][i * 2 + dy] = make_uint2(off, pkbf(wRx * wy, wLx * wy));
        }
    }
    __syncthreads();

    // ---- phase 2: thread = (query, head, d4): 8 channels, 32 pair-iters ----
    const int q = t >> 5, h2 = (t >> 2) & 7, d4 = t & 3;
    int bq = bq0 + q; if (bq > BL_C - 1) bq = BL_C - 1;
    const char* vb = (const char*)value;
    const uint toff = (uint)(h2 * 64 + d4 * 16);

    float a0 = 0.f, a1 = 0.f, a2 = 0.f, a3 = 0.f;
    float a4 = 0.f, a5 = 0.f, a6 = 0.f, a7 = 0.f;
    #pragma unroll 8
    for (int j = 0; j < 32; ++j) {
        const uint2 pw = s_pw[q][h2][j];
        const char* p = vb + (size_t)(pw.x + toff);
        const uint4 v0 = *(const uint4*)p;          // corner L (lo:c0, hi:c1)
        const uint4 v1 = *(const uint4*)(p + 512);  // corner R
        const uint w = pw.y;                        // {lo:wR, hi:wL}
        dot2bf(a0, __builtin_amdgcn_perm(v0.x, v1.x, 0x05040100u), w);
        dot2bf(a1, __builtin_amdgcn_perm(v0.x, v1.x, 0x07060302u), w);
        dot2bf(a2, __builtin_amdgcn_perm(v0.y, v1.y, 0x05040100u), w);
        dot2bf(a3, __builtin_amdgcn_perm(v0.y, v1.y, 0x07060302u), w);
        dot2bf(a4, __builtin_amdgcn_perm(v0.z, v1.z, 0x05040100u), w);
        dot2bf(a5, __builtin_amdgcn_perm(v0.z, v1.z, 0x07060302u), w);
        dot2bf(a6, __builtin_amdgcn_perm(v0.w, v1.w, 0x05040100u), w);
        dot2bf(a7, __builtin_amdgcn_perm(v0.w, v1.w, 0x07060302u), w);
    }
    uint4 o;
    o.x = pkbf(a0, a1); o.y = pkbf(a2, a3);
    o.z = pkbf(a4, a5); o.w = pkbf(a6, a7);
    *(uint4*)(outbf + (size_t)bq * 256 + h2 * 32 + d4 * 8) = o;
}

// ================ fused residual-add + LayerNorm: wave per row ================
template <bool ABF, bool OF32>
__global__ __launch_bounds__(256) void add_ln(
    const void* __restrict__ ap, const ushort* __restrict__ bp,
    const float* __restrict__ g, const float* __restrict__ be,
    void* __restrict__ op)
{
    const int row = blockIdx.x * 4 + (threadIdx.x >> 6);
    if (row >= BL_C) return;
    const int ln = threadIdx.x & 63;
    const size_t base = (size_t)row * 256 + ln * 4;

    float x[4];
    if (ABF) {
        ushort4 a4 = *(const ushort4*)((const ushort*)ap + base);
        x[0] = bf2f(a4.x); x[1] = bf2f(a4.y); x[2] = bf2f(a4.z); x[3] = bf2f(a4.w);
    } else {
        float4 a4 = *(const float4*)((const float*)ap + base);
        x[0] = a4.x; x[1] = a4.y; x[2] = a4.z; x[3] = a4.w;
    }
    ushort4 b4 = *(const ushort4*)(bp + base);
    x[0] += bf2f(b4.x); x[1] += bf2f(b4.y); x[2] += bf2f(b4.z); x[3] += bf2f(b4.w);

    float s = x[0] + x[1] + x[2] + x[3];
    #pragma unroll
    for (int o = 32; o >= 1; o >>= 1) s += __shfl_xor(s, o, 64);
    const float mean = s * (1.f / 256.f);
    float d0 = x[0] - mean, d1 = x[1] - mean, d2 = x[2] - mean, d3 = x[3] - mean;
    float ss = d0 * d0 + d1 * d1 + d2 * d2 + d3 * d3;
    #pragma unroll
    for (int o = 32; o >= 1; o >>= 1) ss += __shfl_xor(ss, o, 64);
    const float rs = rsqrtf(ss * (1.f / 256.f) + 1e-5f);

    float4 gv = *(const float4*)(g + ln * 4);
    float4 bv = *(const float4*)(be + ln * 4);
    float o0 = d0 * rs * gv.x + bv.x;
    float o1 = d1 * rs * gv.y + bv.y;
    float o2 = d2 * rs * gv.z + bv.z;
    float o3 = d3 * rs * gv.w + bv.w;

    if (OF32) {
        *(float4*)((float*)op + base) = make_float4(o0, o1, o2, o3);
    } else {
        ushort4 st;
        st.x = f2bf(o0); st.y = f2bf(o1); st.z = f2bf(o2); st.w = f2bf(o3);
        *(ushort4*)((ushort*)op + base) = st;
    }
}

extern "C" void kernel_launch(void* const* d_in, const int* in_sizes, int n_in,
                              void* d_out, int out_size, void* d_ws, size_t ws_size,
                              hipStream_t stream) {
    const float* src    = (const float*)d_in[0];
    const float* pos    = (const float*)d_in[1];
    const float* refpts = (const float*)d_in[2];
    const float* W_off  = (const float*)d_in[5];
    const float* b_off  = (const float*)d_in[6];
    const float* W_attn = (const float*)d_in[7];
    const float* b_attn = (const float*)d_in[8];
    const float* W_val  = (const float*)d_in[9];
    const float* b_val  = (const float*)d_in[10];
    const float* W_out  = (const float*)d_in[11];
    const float* b_out  = (const float*)d_in[12];
    const float* W1     = (const float*)d_in[13];
    const float* b1     = (const float*)d_in[14];
    const float* W2     = (const float*)d_in[15];
    const float* b2     = (const float*)d_in[16];
    const float* g1     = (const float*)d_in[17];
    const float* be1    = (const float*)d_in[18];
    const float* g2     = (const float*)d_in[19];
    const float* be2    = (const float*)d_in[20];
    float* out = (float*)d_out;
    (void)in_sizes; (void)n_in; (void)out_size; (void)ws_size;

    const int BL = BL_C;
    char* ws = (char*)d_ws;
    const size_t HB  = (size_t)BL * 256 * 2;     // 20.68 MB
    const size_t OAB = (size_t)BL * 384 * 2;     // 31.02 MB

    // regions: A:[q -> x] B:[val] C:[oa] D:[ao] D2:[src2] E:[src_bf -> ffn2]
    ushort* q_bf    = (ushort*)(ws);                       // A
    ushort* x_bf    = (ushort*)(ws);                       // A (q dead after G2)
    ushort* val_bf  = (ushort*)(ws + HB);                  // B
    ushort* oa_bf   = (ushort*)(ws + 2 * HB);              // C
    ushort* ao_bf   = (ushort*)(ws + 2 * HB + OAB);        // D
    ushort* src2_bf = (ushort*)(ws + 3 * HB + OAB);        // D2
    ushort* srcb_bf = (ushort*)(ws + 4 * HB + OAB);        // E
    ushort* ffn2_bf = srcb_bf;                             // E (src_bf dead after LN1)
    ushort* mid_bf  = val_bf;                              // overlays B,C,D,D2 (93 MB)
    char*   wts     = ws + 5 * HB + OAB;
    ushort* Tval = (ushort*)(wts);               // 256x256
    ushort* Toa  = Tval + 256 * 256;             // 384x256
    ushort* Tout = Toa + 384 * 256;              // 256x256
    ushort* TW1  = Tout + 256 * 256;             // 1024x256
    ushort* TW2  = TW1 + 1024 * 256;             // 256x1024
    float*  boa  = (float*)(TW2 + 256 * 1024);   // 384

    dim3 blk(256);
    const int MT = (BL + 127) / 128;   // 316 M-tiles of 128 rows

    // 1) all prep (weights + q + src_bf)
    prep_all<<<dim3(738 + 1024), blk, 0, stream>>>(
        src, pos, W_val, W_off, W_attn, W_out, W1, W2, b_off, b_attn,
        Tval, Toa, Tout, TW1, TW2, boa, q_bf, srcb_bf);

    // 2) G1+G2 fused, B-persistent (L=2): grid = 2*158 + 3*158 = 790
    gemm_dual<<<dim3(2 * 158 + 3 * 158), blk, 0, stream>>>(
        srcb_bf, Tval, b_val, val_bf, 256, 2, 158, 2 * 158,
        q_bf, Toa, boa, oa_bf, 384, 3, 158, 3 * 158);

    // 3) sampling -> ao
    sample_kernel<<<dim3((BL + 7) / 8), blk, 0, stream>>>(val_bf, oa_bf, refpts, ao_bf);

    // 4) G3: src2 = ao @ Wout + b_out  (persistent L=1: 632 blocks keep TLP)
    gemm_pers<1, false><<<dim3(2 * 316), blk, 0, stream>>>(
        ao_bf, Tout, b_out, src2_bf, BL, 256, 2, 316, 2 * 316);

    // 5) LN1: x = LN(src + src2)  (bf16 src residual)
    add_ln<true, false><<<dim3((BL + 3) / 4), blk, 0, stream>>>(
        srcb_bf, src2_bf, g1, be1, x_bf);

    // 6) G4: mid = relu(x @ W1 + b1)  (r18 chunked: 2528 blocks, 32KB — L=4
    //    persistent was 86us at 9.5% occupancy, r19 post-mortem)
    gemm_bs<true><<<dim3(MT * 8), blk, 0, stream>>>(
        x_bf, TW1, b1, mid_bf, BL, 1024, 256, 8, MT * 8);

    // 7) G5: ffn2 = mid @ W2 + b2   (K=1024, chunked)
    gemm_bs<false><<<dim3(MT * 2), blk, 0, stream>>>(
        mid_bf, TW2, b2, ffn2_bf, BL, 256, 1024, 2, MT * 2);

    // 8) LN2: out = LN(x + ffn2) -> f32  (x is bf16)
    add_ln<true, true><<<dim3((BL + 3) / 4), blk, 0, stream>>>(
        x_bf, ffn2_bf, g2, be2, out);
}

// Round 21
// 264.701 us; speedup vs baseline: 1.0301x; 1.0301x over previous
//
#include <hip/hip_runtime.h>
#include <math.h>

#define LEN_IN_C 20197
#define BATCH_C 2
#define BL_C (BATCH_C * LEN_IN_C)   // 40394

typedef short  bf16x8 __attribute__((ext_vector_type(8)));
typedef float  f32x4  __attribute__((ext_vector_type(4)));

__device__ __forceinline__ ushort f2bf(float f) {
    unsigned u = __float_as_uint(f);
    return (ushort)((u + 0x7fffu + ((u >> 16) & 1u)) >> 16);
}
__device__ __forceinline__ float bf2f(ushort u) {
    return __uint_as_float((uint)u << 16);
}
__device__ __forceinline__ uint pkbf(float a, float b) {
    uint r;
    asm("v_cvt_pk_bf16_f32 %0, %1, %2" : "=v"(r) : "v"(a), "v"(b));
    return r;
}
// acc += v.lo*w.lo + v.hi*w.hi  (bf16 pairs, f32 accumulate)
__device__ __forceinline__ void dot2bf(float& a, uint v, uint w) {
    asm("v_dot2_f32_bf16 %0, %1, %2, %0" : "+v"(a) : "v"(v), "v"(w));
}
__device__ __forceinline__ void gload16(const void* g, void* l) {
    __builtin_amdgcn_global_load_lds(
        (const __attribute__((address_space(1))) unsigned char*)g,
        (__attribute__((address_space(3))) unsigned char*)l, 16, 0, 0);
}
__device__ __forceinline__ int xcd_swz(int lid, int nwg) {
    const int q = nwg >> 3, r = nwg & 7;
    const int xcd = lid & 7, p = lid >> 3;
    return (xcd < r ? xcd * (q + 1) : r * (q + 1) + (xcd - r) * q) + p;
}

// ================= combined prep kernel (weights + q + src_bf) =================
__device__ __forceinline__ void tcast32(
    const float* W, ushort* WT, int K, int N, int n0, int k0, float* tile /*32*33*/)
{
    const int ty = threadIdx.x >> 3, tx = threadIdx.x & 7;
    float4 v = *(const float4*)(W + (size_t)(k0 + ty) * N + n0 + tx * 4);
    tile[ty * 33 + tx * 4 + 0] = v.x; tile[ty * 33 + tx * 4 + 1] = v.y;
    tile[ty * 33 + tx * 4 + 2] = v.z; tile[ty * 33 + tx * 4 + 3] = v.w;
    __syncthreads();
    ushort4 o;
    o.x = f2bf(tile[(tx * 4 + 0) * 33 + ty]);
    o.y = f2bf(tile[(tx * 4 + 1) * 33 + ty]);
    o.z = f2bf(tile[(tx * 4 + 2) * 33 + ty]);
    o.w = f2bf(tile[(tx * 4 + 3) * 33 + ty]);
    *(ushort4*)(WT + (size_t)(n0 + ty) * K + k0 + tx * 4) = o;
}

__global__ __launch_bounds__(256) void prep_all(
    const float* __restrict__ src, const float* __restrict__ pos,
    const float* __restrict__ Wv, const float* __restrict__ Wo,
    const float* __restrict__ Wa, const float* __restrict__ Wout,
    const float* __restrict__ W1, const float* __restrict__ W2,
    const float* __restrict__ bo, const float* __restrict__ ba,
    ushort* __restrict__ Tval, ushort* __restrict__ Toa,
    ushort* __restrict__ Tout, ushort* __restrict__ TW1,
    ushort* __restrict__ TW2, float* __restrict__ boa,
    ushort* __restrict__ qout, ushort* __restrict__ srcb)
{
    __shared__ float tile[32 * 33];
    const int bx = blockIdx.x;
    const int tid = threadIdx.x;
    if (bx < 64) {
        tcast32(Wv, Tval, 256, 256, (bx & 7) * 32, (bx >> 3) * 32, tile);
    } else if (bx < 128) {
        const int s = bx - 64;
        tcast32(Wout, Tout, 256, 256, (s & 7) * 32, (s >> 3) * 32, tile);
    } else if (bx < 384) {
        const int s = bx - 128;
        tcast32(W1, TW1, 256, 1024, (s & 31) * 32, (s >> 5) * 32, tile);
    } else if (bx < 640) {
        const int s = bx - 384;
        tcast32(W2, TW2, 1024, 256, (s & 7) * 32, (s >> 3) * 32, tile);
    } else if (bx < 736) {
        const int idx = (bx - 640) * 256 + tid;
        const int n = idx >> 6, k4 = (idx & 63) * 4;
        ushort4 o; ushort* po = (ushort*)&o;
        #pragma unroll
        for (int j = 0; j < 4; ++j) {
            const int k = k4 + j;
            const float v = (n < 256) ? Wo[(size_t)k * 256 + n]
                                      : Wa[(size_t)k * 128 + (n - 256)];
            po[j] = f2bf(v);
        }
        *(ushort4*)(Toa + (size_t)n * 256 + k4) = o;
    } else if (bx < 738) {
        const int n = (bx - 736) * 256 + tid;
        if (n < 384) boa[n] = (n < 256) ? bo[n] : ba[n - 256];
    } else {
        const int n8 = BL_C * 32;
        for (int i = (bx - 738) * 256 + tid; i < n8; i += 1024 * 256) {
            const size_t base = (size_t)i * 8;
            float4 a0 = *(const float4*)(src + base);
            float4 a1 = *(const float4*)(src + base + 4);
            float4 b0 = *(const float4*)(pos + base);
            float4 b1 = *(const float4*)(pos + base + 4);
            uint4 o;
            o.x = pkbf(a0.x + b0.x, a0.y + b0.y);
            o.y = pkbf(a0.z + b0.z, a0.w + b0.w);
            o.z = pkbf(a1.x + b1.x, a1.y + b1.y);
            o.w = pkbf(a1.z + b1.z, a1.w + b1.w);
            *(uint4*)(qout + base) = o;
            uint4 s4;
            s4.x = pkbf(a0.x, a0.y); s4.y = pkbf(a0.z, a0.w);
            s4.z = pkbf(a1.x, a1.y); s4.w = pkbf(a1.z, a1.w);
            *(uint4*)(srcb + base) = s4;
        }
    }
}

// ====== B-stationary chunked MFMA GEMM (round-18 measured best): ======
// m=2, n=8 (BN=128), KC=128, 32KB LDS. Block = 128 rows x 128 cols, 4 waves
// stacked in M. Per chunk: full-chunk A prefetch (8 loads, no LDS dep),
// stage B (8 gload16), one __syncthreads (vmcnt(0) drains both), pure
// regs+LDS K-loop (4 steps x 16 MFMA).
template <bool RELU>
__device__ __forceinline__ void gemm_core(
    ushort* lsB, const int lid,
    const ushort* __restrict__ A, const ushort* __restrict__ BT,
    const float* __restrict__ bias, ushort* __restrict__ C,
    const int M, const int N, const int K, const int NT, const int nwg)
{
    const int nid = xcd_swz(lid, nwg);
    const int nt = nid % NT, mt = nid / NT;
    const int row0 = mt * 128, col0 = nt * 128;

    const int tid = threadIdx.x;
    const int ln = tid & 63, wv = tid >> 6;
    const int l16 = ln & 15, lk = ln >> 4;

    uint abase[2];
    #pragma unroll
    for (int m = 0; m < 2; ++m) {
        int rr = row0 + wv * 32 + m * 16 + l16;
        if (rr > M - 1) rr = M - 1;
        abase[m] = (uint)rr * K + lk * 8;
    }
    uint bbase[8], bxor[8];
    #pragma unroll
    for (int n = 0; n < 8; ++n) {
        const int brow = n * 16 + l16;
        bbase[n] = (uint)(brow * 256 + lk * 16);
        bxor[n]  = (uint)((brow & 7) << 4);
    }

    f32x4 acc[2][8] = {};
    const int nch = K >> 7;

    for (int ch = 0; ch < nch; ++ch) {
        const int kc0 = ch << 7;

        bf16x8 ar[4][2];
        #pragma unroll
        for (int s = 0; s < 4; ++s)
            #pragma unroll
            for (int m = 0; m < 2; ++m)
                ar[s][m] = *(const bf16x8*)(A + abase[m] + kc0 + s * 32);

        if (ch) __syncthreads();
        #pragma unroll
        for (int j = 0; j < 8; ++j) {
            const int d = j * 256 + tid;
            const int brow = d >> 4;
            const int c = (d & 15) ^ (brow & 7);
            gload16(BT + (size_t)(col0 + brow) * K + kc0 + c * 8,
                    (char*)lsB + j * 4096 + wv * 1024);
        }
        __syncthreads();   // drains vmcnt(0): B in LDS AND A in regs

        #pragma unroll
        for (int gs = 0; gs < 4; ++gs) {
            bf16x8 bv[8];
            #pragma unroll
            for (int n = 0; n < 8; ++n)
                bv[n] = *(const bf16x8*)((const char*)lsB +
                        ((bbase[n] + gs * 64) ^ bxor[n]));
            #pragma unroll
            for (int m = 0; m < 2; ++m)
                #pragma unroll
                for (int n = 0; n < 8; ++n)
                    acc[m][n] = __builtin_amdgcn_mfma_f32_16x16x32_bf16(
                        bv[n], ar[gs][m], acc[m][n], 0, 0, 0);
        }
    }

    #pragma unroll
    for (int m = 0; m < 2; ++m) {
        const int grow = row0 + wv * 32 + m * 16 + l16;
        if (grow >= M) continue;
        ushort* crow = C + (size_t)grow * N;
        #pragma unroll
        for (int n = 0; n < 8; ++n) {
            const int col4 = col0 + n * 16 + lk * 4;
            float4 bs = *(const float4*)(bias + col4);
            f32x4 v = acc[m][n];
            float o0 = v[0] + bs.x, o1 = v[1] + bs.y, o2 = v[2] + bs.z, o3 = v[3] + bs.w;
            if (RELU) {
                o0 = fmaxf(o0, 0.f); o1 = fmaxf(o1, 0.f);
                o2 = fmaxf(o2, 0.f); o3 = fmaxf(o3, 0.f);
            }
            *(uint2*)(crow + col4) = make_uint2(pkbf(o0, o1), pkbf(o2, o3));
        }
    }
}

template <bool RELU>
__global__ __launch_bounds__(256) void gemm_bs(
    const ushort* __restrict__ A, const ushort* __restrict__ BT,
    const float* __restrict__ bias, ushort* __restrict__ C,
    const int M, const int N, const int K, const int NT, const int nwg)
{
    __shared__ ushort lsB[128 * 128];   // 32KB
    gemm_core<RELU>(lsB, blockIdx.x, A, BT, bias, C, M, N, K, NT, nwg);
}

// Dual-task GEMM: blocks [0,nwg1) run task 1, [nwg1,nwg1+nwg2) run task 2.
// nwg1 must be a multiple of 8 so task 2's XCD swizzle stays aligned.
__global__ __launch_bounds__(256) void gemm_dual(
    const ushort* __restrict__ A1, const ushort* __restrict__ BT1,
    const float* __restrict__ b1, ushort* __restrict__ C1,
    const int N1, const int NT1, const int nwg1,
    const ushort* __restrict__ A2, const ushort* __restrict__ BT2,
    const float* __restrict__ b2, ushort* __restrict__ C2,
    const int N2, const int NT2, const int nwg2)
{
    __shared__ ushort lsB[128 * 128];   // 32KB
    if ((int)blockIdx.x < nwg1)
        gemm_core<false>(lsB, blockIdx.x, A1, BT1, b1, C1, BL_C, N1, 256, NT1, nwg1);
    else
        gemm_core<false>(lsB, blockIdx.x - nwg1, A2, BT2, b2, C2, BL_C, N2, 256, NT2, nwg2);
}

// ================= MS-deformable sampling: 1 block = 8 queries =================
__global__ __launch_bounds__(256) void sample_kernel(
    const ushort* __restrict__ value,    // (B, L, 256) bf16
    const ushort* __restrict__ oa,       // (BL, 384) bf16: [off 256 | attn 128]
    const float* __restrict__ ref,       // (BL, 8)
    ushort* __restrict__ outbf)          // (BL, 256) bf16
{
    constexpr int Hs[4] = {100, 50, 25, 13};
    constexpr int Ws[4] = {152, 76, 38, 19};
    constexpr int St[4] = {0, 15200, 19000, 19950};
    constexpr int NWG = (BL_C + 7) / 8;    // 5050

    const int bq0 = xcd_swz(blockIdx.x, NWG) * 8;
    const int t = threadIdx.x;

    __shared__ uint2 s_pw[8][8][33];   // [q][h][pair j=i*2+dy], 16.9 KB

    // ---- phase 1: 4 rounds x 2 queries; each lane owns one (h, l, p) ----
    #pragma unroll
    for (int rnd = 0; rnd < 4; ++rnd) {
        const int qi2 = t >> 7, r2 = t & 127;
        const int qloc = rnd * 2 + qi2;
        int bq = bq0 + qloc; if (bq > BL_C - 1) bq = BL_C - 1;
        const int b = (bq >= LEN_IN_C) ? 1 : 0;
        const int h = r2 >> 4, i = r2 & 15, l = i >> 2, p = i & 3;
        const ushort* crow = oa + (size_t)bq * 384;

        float lg = bf2f(crow[256 + h * 16 + i]);
        float mx = lg;
        #pragma unroll
        for (int o = 1; o < 16; o <<= 1) mx = fmaxf(mx, __shfl_xor(mx, o, 16));
        float e = __expf(lg - mx), sm = e;
        #pragma unroll
        for (int o = 1; o < 16; o <<= 1) sm += __shfl_xor(sm, o, 16);
        const float aw = e / sm;

        const uint ov = *(const uint*)(crow + h * 32 + l * 8 + p * 2);
        const float ox = __uint_as_float(ov << 16);
        const float oy = __uint_as_float(ov & 0xffff0000u);
        const float2 rxy = *(const float2*)(ref + (size_t)bq * 8 + l * 2);
        const int H = Hs[l], W = Ws[l];
        const float x = rxy.x * (float)W + ox - 0.5f;
        const float y = rxy.y * (float)H + oy - 0.5f;
        const float x0f = floorf(x), y0f = floorf(y);
        const float fx = x - x0f, fy = y - y0f;
        const int x0 = (int)x0f, y0 = (int)y0f;

        const float wx0 = (x0 >= 0 && x0 < W) ? (1.f - fx) : 0.f;
        const float wx1 = (x0 + 1 >= 0 && x0 + 1 < W) ? fx : 0.f;
        int xb = x0 < 0 ? 0 : (x0 > W - 2 ? W - 2 : x0);
        float wLx = (xb == x0) ? wx0 : ((xb == x0 + 1) ? wx1 : 0.f);
        float wRx = (xb + 1 == x0 + 1) ? wx1 : ((xb + 1 == x0) ? wx0 : 0.f);
        wLx *= aw; wRx *= aw;

        const uint rowb = (uint)(b * LEN_IN_C + St[l] + xb);
        #pragma unroll
        for (int dy = 0; dy < 2; ++dy) {
            const int yy = y0 + dy;
            const bool vy = (yy >= 0) & (yy < H);
            const float wy = vy ? (dy ? fy : 1.f - fy) : 0.f;
            const int yc = yy < 0 ? 0 : (yy > H - 1 ? H - 1 : yy);
            const uint off = (rowb + (uint)(yc * W)) * 512u;
            // bf16 pair, order (lo=wR, hi=wL) to match perm output {lo:vR, hi:vL}
            s_pw[qloc][h][i * 2 + dy] = make_uint2(off, pkbf(wRx * wy, wLx * wy));
        }
    }
    __syncthreads();

    // ---- phase 2: thread = (query, head, d4): 8 channels, 32 pair-iters ----
    const int q = t >> 5, h2 = (t >> 2) & 7, d4 = t & 3;
    int bq = bq0 + q; if (bq > BL_C - 1) bq = BL_C - 1;
    const char* vb = (const char*)value;
    const uint toff = (uint)(h2 * 64 + d4 * 16);

    float a0 = 0.f, a1 = 0.f, a2 = 0.f, a3 = 0.f;
    float a4 = 0.f, a5 = 0.f, a6 = 0.f, a7 = 0.f;
    #pragma unroll 8
    for (int j = 0; j < 32; ++j) {
        const uint2 pw = s_pw[q][h2][j];
        const char* p = vb + (size_t)(pw.x + toff);
        const uint4 v0 = *(const uint4*)p;          // corner L (lo:c0, hi:c1)
        const uint4 v1 = *(const uint4*)(p + 512);  // corner R
        const uint w = pw.y;                        // {lo:wR, hi:wL}
        dot2bf(a0, __builtin_amdgcn_perm(v0.x, v1.x, 0x05040100u), w);
        dot2bf(a1, __builtin_amdgcn_perm(v0.x, v1.x, 0x07060302u), w);
        dot2bf(a2, __builtin_amdgcn_perm(v0.y, v1.y, 0x05040100u), w);
        dot2bf(a3, __builtin_amdgcn_perm(v0.y, v1.y, 0x07060302u), w);
        dot2bf(a4, __builtin_amdgcn_perm(v0.z, v1.z, 0x05040100u), w);
        dot2bf(a5, __builtin_amdgcn_perm(v0.z, v1.z, 0x07060302u), w);
        dot2bf(a6, __builtin_amdgcn_perm(v0.w, v1.w, 0x05040100u), w);
        dot2bf(a7, __builtin_amdgcn_perm(v0.w, v1.w, 0x07060302u), w);
    }
    uint4 o;
    o.x = pkbf(a0, a1); o.y = pkbf(a2, a3);
    o.z = pkbf(a4, a5); o.w = pkbf(a6, a7);
    *(uint4*)(outbf + (size_t)bq * 256 + h2 * 32 + d4 * 8) = o;
}

// ================ fused residual-add + LayerNorm: wave per row ================
template <bool ABF, bool OF32>
__global__ __launch_bounds__(256) void add_ln(
    const void* __restrict__ ap, const ushort* __restrict__ bp,
    const float* __restrict__ g, const float* __restrict__ be,
    void* __restrict__ op)
{
    const int row = blockIdx.x * 4 + (threadIdx.x >> 6);
    if (row >= BL_C) return;
    const int ln = threadIdx.x & 63;
    const size_t base = (size_t)row * 256 + ln * 4;

    float x[4];
    if (ABF) {
        ushort4 a4 = *(const ushort4*)((const ushort*)ap + base);
        x[0] = bf2f(a4.x); x[1] = bf2f(a4.y); x[2] = bf2f(a4.z); x[3] = bf2f(a4.w);
    } else {
        float4 a4 = *(const float4*)((const float*)ap + base);
        x[0] = a4.x; x[1] = a4.y; x[2] = a4.z; x[3] = a4.w;
    }
    ushort4 b4 = *(const ushort4*)(bp + base);
    x[0] += bf2f(b4.x); x[1] += bf2f(b4.y); x[2] += bf2f(b4.z); x[3] += bf2f(b4.w);

    float s = x[0] + x[1] + x[2] + x[3];
    #pragma unroll
    for (int o = 32; o >= 1; o >>= 1) s += __shfl_xor(s, o, 64);
    const float mean = s * (1.f / 256.f);
    float d0 = x[0] - mean, d1 = x[1] - mean, d2 = x[2] - mean, d3 = x[3] - mean;
    float ss = d0 * d0 + d1 * d1 + d2 * d2 + d3 * d3;
    #pragma unroll
    for (int o = 32; o >= 1; o >>= 1) ss += __shfl_xor(ss, o, 64);
    const float rs = rsqrtf(ss * (1.f / 256.f) + 1e-5f);

    float4 gv = *(const float4*)(g + ln * 4);
    float4 bv = *(const float4*)(be + ln * 4);
    float o0 = d0 * rs * gv.x + bv.x;
    float o1 = d1 * rs * gv.y + bv.y;
    float o2 = d2 * rs * gv.z + bv.z;
    float o3 = d3 * rs * gv.w + bv.w;

    if (OF32) {
        *(float4*)((float*)op + base) = make_float4(o0, o1, o2, o3);
    } else {
        ushort4 st;
        st.x = f2bf(o0); st.y = f2bf(o1); st.z = f2bf(o2); st.w = f2bf(o3);
        *(ushort4*)((ushort*)op + base) = st;
    }
}

extern "C" void kernel_launch(void* const* d_in, const int* in_sizes, int n_in,
                              void* d_out, int out_size, void* d_ws, size_t ws_size,
                              hipStream_t stream) {
    const float* src    = (const float*)d_in[0];
    const float* pos    = (const float*)d_in[1];
    const float* refpts = (const float*)d_in[2];
    const float* W_off  = (const float*)d_in[5];
    const float* b_off  = (const float*)d_in[6];
    const float* W_attn = (const float*)d_in[7];
    const float* b_attn = (const float*)d_in[8];
    const float* W_val  = (const float*)d_in[9];
    const float* b_val  = (const float*)d_in[10];
    const float* W_out  = (const float*)d_in[11];
    const float* b_out  = (const float*)d_in[12];
    const float* W1     = (const float*)d_in[13];
    const float* b1     = (const float*)d_in[14];
    const float* W2     = (const float*)d_in[15];
    const float* b2     = (const float*)d_in[16];
    const float* g1     = (const float*)d_in[17];
    const float* be1    = (const float*)d_in[18];
    const float* g2     = (const float*)d_in[19];
    const float* be2    = (const float*)d_in[20];
    float* out = (float*)d_out;
    (void)in_sizes; (void)n_in; (void)out_size; (void)ws_size;

    const int BL = BL_C;
    char* ws = (char*)d_ws;
    const size_t HB  = (size_t)BL * 256 * 2;     // 20.68 MB
    const size_t OAB = (size_t)BL * 384 * 2;     // 31.02 MB

    // regions: A:[q -> x] B:[val] C:[oa] D:[ao] D2:[src2] E:[src_bf -> ffn2]
    ushort* q_bf    = (ushort*)(ws);                       // A
    ushort* x_bf    = (ushort*)(ws);                       // A (q dead after G2)
    ushort* val_bf  = (ushort*)(ws + HB);                  // B
    ushort* oa_bf   = (ushort*)(ws + 2 * HB);              // C
    ushort* ao_bf   = (ushort*)(ws + 2 * HB + OAB);        // D
    ushort* src2_bf = (ushort*)(ws + 3 * HB + OAB);        // D2
    ushort* srcb_bf = (ushort*)(ws + 4 * HB + OAB);        // E
    ushort* ffn2_bf = srcb_bf;                             // E (src_bf dead after LN1)
    ushort* mid_bf  = val_bf;                              // overlays B,C,D,D2 (93 MB)
    char*   wts     = ws + 5 * HB + OAB;
    ushort* Tval = (ushort*)(wts);               // 256x256
    ushort* Toa  = Tval + 256 * 256;             // 384x256
    ushort* Tout = Toa + 384 * 256;              // 256x256
    ushort* TW1  = Tout + 256 * 256;             // 1024x256
    ushort* TW2  = TW1 + 1024 * 256;             // 256x1024
    float*  boa  = (float*)(TW2 + 256 * 1024);   // 384

    dim3 blk(256);
    const int MT = (BL + 127) / 128;   // 316

    // 1) all prep (weights + q + src_bf)
    prep_all<<<dim3(738 + 1024), blk, 0, stream>>>(
        src, pos, W_val, W_off, W_attn, W_out, W1, W2, b_off, b_attn,
        Tval, Toa, Tout, TW1, TW2, boa, q_bf, srcb_bf);

    // 2) G1+G2 fused: value = srcb @ Wv + bv  AND  [off|attn] = q @ [Wo|Wa] + boa
    //    nwg1 = 316*2 = 632 (multiple of 8 -> task-2 swizzle stays aligned)
    gemm_dual<<<dim3(MT * 2 + MT * 3), blk, 0, stream>>>(
        srcb_bf, Tval, b_val, val_bf, 256, 2, MT * 2,
        q_bf, Toa, boa, oa_bf, 384, 3, MT * 3);

    // 3) sampling -> ao
    sample_kernel<<<dim3((BL + 7) / 8), blk, 0, stream>>>(val_bf, oa_bf, refpts, ao_bf);

    // 4) G3: src2 = ao @ Wout + b_out
    gemm_bs<false><<<dim3(MT * 2), blk, 0, stream>>>(
        ao_bf, Tout, b_out, src2_bf, BL, 256, 256, 2, MT * 2);

    // 5) LN1: x = LN(src + src2)  (bf16 src residual)
    add_ln<true, false><<<dim3((BL + 3) / 4), blk, 0, stream>>>(
        srcb_bf, src2_bf, g1, be1, x_bf);

    // 6) G4: mid = relu(x @ W1 + b1)   (mid overlays val/oa/ao/src2)
    gemm_bs<true><<<dim3(MT * 8), blk, 0, stream>>>(
        x_bf, TW1, b1, mid_bf, BL, 1024, 256, 8, MT * 8);

    // 7) G5: ffn2 = mid @ W2 + b2   (overlays src_bf)
    gemm_bs<false><<<dim3(MT * 2), blk, 0, stream>>>(
        mid_bf, TW2, b2, ffn2_bf, BL, 256, 1024, 2, MT * 2);

    // 8) LN2: out = LN(x + ffn2) -> f32  (x is bf16)
    add_ln<true, true><<<dim3((BL + 3) / 4), blk, 0, stream>>>(
        x_bf, ffn2_bf, g2, be2, out);
}